// Round 12
// baseline (212.768 us; speedup 1.0000x reference)
//
#include <hip/hip_runtime.h>

using u16 = unsigned short;
typedef __attribute__((ext_vector_type(8))) short short8;
typedef __attribute__((ext_vector_type(4))) float floatx4;

#define NQ 1024
#define NK 2048
#define DD 512

__device__ __forceinline__ float bf2f(u16 u) {
  union { unsigned u; float f; } x; x.u = ((unsigned)u) << 16; return x.f;
}
// packed RTNE f32x2 -> bf16x2 (bits[15:0]=lo, [31:16]=hi)
__device__ __forceinline__ unsigned cvt_pk_bf16(float lo, float hi) {
  unsigned r;
  asm("v_cvt_pk_bf16_f32 %0, %1, %2" : "=v"(r) : "v"(lo), "v"(hi));
  return r;
}
__device__ __forceinline__ float wave_sum(float v) {
#pragma unroll
  for (int off = 32; off > 0; off >>= 1) v += __shfl_down(v, off, 64);
  return v;
}
__device__ __forceinline__ void gload16(const u16* g, const u16* l) {
  __builtin_amdgcn_global_load_lds(
      (const __attribute__((address_space(1))) void*)g,
      (__attribute__((address_space(3))) void*)l, 16, 0, 0);
}

// ---- fused: wave-per-row LN (inputs+context) + weight cvt + zero Z/colV ----
__global__ __launch_bounds__(256) void ln_prep(
    const float* __restrict__ X1, const float* __restrict__ G1,
    const float* __restrict__ B1, u16* __restrict__ Y1,
    const float* __restrict__ X2, const float* __restrict__ G2,
    const float* __restrict__ B2, u16* __restrict__ Y2,
    const float* __restrict__ Wq, const float* __restrict__ Wk,
    const float* __restrict__ Wv, u16* __restrict__ wqb,
    u16* __restrict__ wkb, u16* __restrict__ wvb, float* __restrict__ Zero,
    float qsc) {
  const int bx = blockIdx.x;
  const int t = threadIdx.x;
  if (bx >= 6144) {
    int e = bx - 6144;
    if (e < 768) {
      const float* src = e < 256 ? Wq : (e < 512 ? Wk : Wv);
      u16* dst = e < 256 ? wqb : (e < 512 ? wkb : wvb);
      const float ws = e < 256 ? qsc : 1.f;
      int i = ((e & 255) * 256 + t) * 4;
      float4 v = *(const float4*)(src + i);
      union { unsigned u[2]; ushort4 s; } ou;
      ou.u[0] = cvt_pk_bf16(v.x * ws, v.y * ws);
      ou.u[1] = cvt_pk_bf16(v.z * ws, v.w * ws);
      *(ushort4*)(dst + i) = ou.s;
    } else {
      int i = ((e - 768) * 256 + t) * 4;
      float4 z = {0.f, 0.f, 0.f, 0.f};
      *(float4*)(Zero + i) = z;
    }
    return;
  }
  const int wave = t >> 6, lane = t & 63;
  int row = bx * 4 + wave;
  const float *X, *G, *Bv; u16* Y;
  if (row < 8192) { X = X1; G = G1; Bv = B1; Y = Y1; }
  else { row -= 8192; X = X2; G = G2; Bv = B2; Y = Y2; }
  const float4* Xp = (const float4*)(X + (long)row * DD);
  float4 v0 = Xp[lane * 2], v1 = Xp[lane * 2 + 1];
  float s = v0.x + v0.y + v0.z + v0.w + v1.x + v1.y + v1.z + v1.w;
  float ss = v0.x * v0.x + v0.y * v0.y + v0.z * v0.z + v0.w * v0.w +
             v1.x * v1.x + v1.y * v1.y + v1.z * v1.z + v1.w * v1.w;
  s = wave_sum(s);  s = __shfl(s, 0, 64);
  ss = wave_sum(ss); ss = __shfl(ss, 0, 64);
  float mu = s * (1.f / DD);
  float var = ss * (1.f / DD) - mu * mu;
  float rs = rsqrtf(var + 1e-5f);
  const float4* Gp = (const float4*)G;
  const float4* Bp = (const float4*)Bv;
  float4 g0 = Gp[lane * 2], g1 = Gp[lane * 2 + 1];
  float4 b0 = Bp[lane * 2], b1 = Bp[lane * 2 + 1];
  union { unsigned u[4]; short8 s8; } ou;
  ou.u[0] = cvt_pk_bf16((v0.x - mu) * rs * g0.x + b0.x,
                        (v0.y - mu) * rs * g0.y + b0.y);
  ou.u[1] = cvt_pk_bf16((v0.z - mu) * rs * g0.z + b0.z,
                        (v0.w - mu) * rs * g0.w + b0.w);
  ou.u[2] = cvt_pk_bf16((v1.x - mu) * rs * g1.x + b1.x,
                        (v1.y - mu) * rs * g1.y + b1.y);
  ou.u[3] = cvt_pk_bf16((v1.z - mu) * rs * g1.z + b1.z,
                        (v1.w - mu) * rs * g1.w + b1.w);
  *(short8*)(Y + (long)row * DD + lane * 8) = ou.s8;
}

// ---- proj_all: q-proj (blocks 0..255, 128x128) + merged k&v proj
// (256..1279, 128 ctx-rows x 64 d-cols, cb staged ONCE for both Wk and Wv).
// k out: kb[j][d]. v out: vT[b][d][j] (transposed stage) + colV row sums.
__global__ __launch_bounds__(256) void proj_all(
    const u16* __restrict__ xb, const u16* __restrict__ wqb,
    const float* __restrict__ bq, u16* __restrict__ qb,
    const u16* __restrict__ cb, const u16* __restrict__ wkb,
    const float* __restrict__ bk, u16* __restrict__ kb,
    const u16* __restrict__ wvb, const float* __restrict__ bv,
    u16* __restrict__ vT, float* __restrict__ colV, float qsc) {
  __shared__ u16 smem[16384];
  const int bx = blockIdx.x;
  const int t = threadIdx.x, wave = t >> 6, lane = t & 63;
  const int fm = lane & 15, fq = lane >> 4;
  const int srow = t >> 3;
  const int swz = ((t & 7) ^ (srow & 7)) * 8;

  if (bx < 256) {
    // ---------------- q path: 128x128, identical to proven gemm_proj -------
    u16* lA = smem;
    u16* lB = smem + 8192;
    const int m0 = (bx >> 2) * 128, n0 = (bx & 3) * 128;
    const int wm = (wave >> 1) * 64, wn = (wave & 1) * 64;
    const u16* gA = xb + (long)(m0 + srow) * 512 + swz;
    const u16* gB = wqb + (long)(n0 + srow) * 512 + swz;
    u16* dA = lA + wave * 512;
    u16* dB = lB + wave * 512;

    floatx4 acc[4][4];
#pragma unroll
    for (int x = 0; x < 4; ++x)
#pragma unroll
      for (int y = 0; y < 4; ++y) { floatx4 z = {0.f,0.f,0.f,0.f}; acc[x][y] = z; }

#pragma unroll 1
    for (int kt = 0; kt < 8; ++kt) {
      gload16(gA, dA);
      gload16(gA + 32L * 512, dA + 2048);
      gload16(gA + 64L * 512, dA + 4096);
      gload16(gA + 96L * 512, dA + 6144);
      gload16(gB, dB);
      gload16(gB + 32L * 512, dB + 2048);
      gload16(gB + 64L * 512, dB + 4096);
      gload16(gB + 96L * 512, dB + 6144);
      gA += 64; gB += 64;
      __syncthreads();
#pragma unroll
      for (int ks = 0; ks < 2; ++ks) {
        short8 af[4], bfr[4];
        const int csl = ((ks * 4 + fq) ^ (fm & 7)) * 8;
#pragma unroll
        for (int x = 0; x < 4; ++x)
          af[x] = *(const short8*)&lA[(wm + x * 16 + fm) * 64 + csl];
#pragma unroll
        for (int y = 0; y < 4; ++y)
          bfr[y] = *(const short8*)&lB[(wn + y * 16 + fm) * 64 + csl];
#pragma unroll
        for (int x = 0; x < 4; ++x)
#pragma unroll
          for (int y = 0; y < 4; ++y)
            acc[x][y] = __builtin_amdgcn_mfma_f32_16x16x32_bf16(af[x], bfr[y], acc[x][y], 0, 0, 0);
      }
      __syncthreads();
    }

    float bs[4];
    int cs[4];
#pragma unroll
    for (int y = 0; y < 4; ++y) {
      bs[y] = bq[n0 + wn + y * 16 + fm] * qsc;
      cs[y] = ((((wn >> 4) + y) ^ fq) * 16) + fm;
    }
#pragma unroll
    for (int x = 0; x < 4; ++x)
#pragma unroll
      for (int r = 0; r < 4; ++r) {
        int rowl = wm + x * 16 + fq * 4 + r;
        unsigned p01 = cvt_pk_bf16(acc[x][0][r] + bs[0], acc[x][1][r] + bs[1]);
        unsigned p23 = cvt_pk_bf16(acc[x][2][r] + bs[2], acc[x][3][r] + bs[3]);
        smem[rowl * 128 + cs[0]] = (u16)p01;
        smem[rowl * 128 + cs[1]] = (u16)(p01 >> 16);
        smem[rowl * 128 + cs[2]] = (u16)p23;
        smem[rowl * 128 + cs[3]] = (u16)(p23 >> 16);
      }
    __syncthreads();
#pragma unroll
    for (int p = 0; p < 8; ++p) {
      int rowl = p * 16 + (t >> 4);
      int c = t & 15;
      int q = (rowl >> 2) & 3;
      short8 v = *(const short8*)&smem[rowl * 128 + (((c >> 1) ^ q) * 16) + (c & 1) * 8];
      *(short8*)(qb + (long)(m0 + rowl) * 512 + n0 + c * 8) = v;
    }
  } else {
    // -------- merged kv path: A=cb (128 rows), B=wkb & wvb (64 cols) -------
    const int e = bx - 256;
    const int j0 = (e >> 3) * 128, d0 = (e & 7) * 64;
    const int bb = j0 >> 11, j0c = j0 & 2047;
    u16* lA = smem;             // 128x64 u16 (16 KB)
    u16* lK = smem + 8192;      // 64x64  (8 KB)
    u16* lV = smem + 12288;     // 64x64  (8 KB)
    const int wm = (wave >> 1) * 64, wn = (wave & 1) * 32;
    const u16* gA = cb + (long)(j0 + srow) * 512 + swz;
    const u16* gK = wkb + (long)(d0 + srow) * 512 + swz;
    const u16* gV = wvb + (long)(d0 + srow) * 512 + swz;
    u16* dA = lA + wave * 512;
    u16* dK = lK + wave * 512;
    u16* dV = lV + wave * 512;

    floatx4 aK[4][2], aV[4][2];
#pragma unroll
    for (int x = 0; x < 4; ++x)
#pragma unroll
      for (int y = 0; y < 2; ++y) {
        floatx4 z = {0.f, 0.f, 0.f, 0.f};
        aK[x][y] = z; aV[x][y] = z;
      }

#pragma unroll 1
    for (int kt = 0; kt < 8; ++kt) {
      gload16(gA, dA);
      gload16(gA + 32L * 512, dA + 2048);
      gload16(gA + 64L * 512, dA + 4096);
      gload16(gA + 96L * 512, dA + 6144);
      gload16(gK, dK);
      gload16(gK + 32L * 512, dK + 2048);
      gload16(gV, dV);
      gload16(gV + 32L * 512, dV + 2048);
      gA += 64; gK += 64; gV += 64;
      __syncthreads();
#pragma unroll
      for (int ks = 0; ks < 2; ++ks) {
        short8 af[4], bk8[2], bv8[2];
        const int csl = ((ks * 4 + fq) ^ (fm & 7)) * 8;
#pragma unroll
        for (int x = 0; x < 4; ++x)
          af[x] = *(const short8*)&lA[(wm + x * 16 + fm) * 64 + csl];
#pragma unroll
        for (int y = 0; y < 2; ++y) {
          bk8[y] = *(const short8*)&lK[(wn + y * 16 + fm) * 64 + csl];
          bv8[y] = *(const short8*)&lV[(wn + y * 16 + fm) * 64 + csl];
        }
#pragma unroll
        for (int x = 0; x < 4; ++x)
#pragma unroll
          for (int y = 0; y < 2; ++y) {
            aK[x][y] = __builtin_amdgcn_mfma_f32_16x16x32_bf16(af[x], bk8[y], aK[x][y], 0, 0, 0);
            aV[x][y] = __builtin_amdgcn_mfma_f32_16x16x32_bf16(af[x], bv8[y], aV[x][y], 0, 0, 0);
          }
      }
      __syncthreads();
    }

    // epilogue: sK [128 rows j][64 cols d] + sV [64 rows d][128 cols j]
    u16* sK = smem;            // 16 KB
    u16* sV = smem + 8192;     // 16 KB
    float bks[2], bvs[2];
    int dloc[2];
#pragma unroll
    for (int y = 0; y < 2; ++y) {
      dloc[y] = wn + y * 16 + fm;
      bks[y] = bk[d0 + dloc[y]];
      bvs[y] = bv[d0 + dloc[y]];
    }
    float cva[2] = {0.f, 0.f};
#pragma unroll
    for (int x = 0; x < 4; ++x)
#pragma unroll
      for (int r = 0; r < 4; ++r) {
        int rowl = wm + x * 16 + fq * 4 + r;   // j local 0..127
        float vk0 = aK[x][0][r] + bks[0];
        float vk1 = aK[x][1][r] + bks[1];
        float vv0 = aV[x][0][r] + bvs[0];
        float vv1 = aV[x][1][r] + bvs[1];
        cva[0] += vv0; cva[1] += vv1;
        unsigned pk = cvt_pk_bf16(vk0, vk1);
        unsigned pv = cvt_pk_bf16(vv0, vv1);
        // k stage: row j, col d, 64-wide XOR swizzle (proven pattern)
        const int ck0 = ((((wn >> 4) + 0) ^ fq) * 16) + fm;
        const int ck1 = ((((wn >> 4) + 1) ^ fq) * 16) + fm;
        sK[rowl * 64 + ck0] = (u16)pk;
        sK[rowl * 64 + ck1] = (u16)(pk >> 16);
        // v stage TRANSPOSED: row d, col j, swizzle j-block by (d&7)
        const int jblk = rowl >> 4, jin = rowl & 15;
        sV[dloc[0] * 128 + ((jblk ^ (dloc[0] & 7)) * 16) + jin] = (u16)pv;
        sV[dloc[1] * 128 + ((jblk ^ (dloc[1] & 7)) * 16) + jin] = (u16)(pv >> 16);
      }
    __syncthreads();
    // store kb: 128 rows x 64 cols
#pragma unroll
    for (int p = 0; p < 4; ++p) {
      int rowl = p * 32 + (t >> 3);
      int c = t & 7;
      int q = (rowl >> 2) & 3;
      short8 v = *(const short8*)&sK[rowl * 64 + (((c >> 1) ^ q) * 16) + (c & 1) * 8];
      *(short8*)(kb + (long)(j0 + rowl) * 512 + d0 + c * 8) = v;
    }
    // store vT: 64 rows (d) x 128 cols (j)
    u16* Vg = vT + (long)bb * (512L * 2048) + j0c;
#pragma unroll
    for (int p = 0; p < 4; ++p) {
      int d = p * 16 + (t >> 4);
      int c = t & 15;
      short8 v = *(const short8*)&sV[d * 128 + (((c >> 1) ^ (d & 7)) * 16) + (c & 1) * 8];
      *(short8*)(Vg + (long)(d0 + d) * 2048 + c * 8) = v;
    }
    // colV: reduce over fq within wave, atomic per wave half
#pragma unroll
    for (int y = 0; y < 2; ++y) {
      float s = cva[y];
      s += __shfl_xor(s, 16, 64);
      s += __shfl_xor(s, 32, 64);
      if (fq == 0) atomicAdd(&colV[bb * 512 + d0 + dloc[y]], s);
    }
  }
}

// ---------------- QK: E = exp2(q.k^T), Z[j] col sums (atomics) --------------
__global__ __launch_bounds__(256) void gemm_qk(
    const u16* __restrict__ qb, const u16* __restrict__ kb,
    u16* __restrict__ E, float* __restrict__ Z) {
  __shared__ u16 smem[16384];
  u16* lA = smem;
  u16* lB = smem + 8192;

  const int bx = blockIdx.x;
  const int b = bx & 7;
  const int n0 = ((bx >> 3) & 15) * 128;
  const int m0 = (bx >> 7) * 128;
  const u16* A = qb + (long)b * (1024L * 512);
  const u16* B = kb + (long)b * (2048L * 512);

  const int t = threadIdx.x, wave = t >> 6, lane = t & 63;
  const int fm = lane & 15, fq = lane >> 4;
  const int wm = (wave >> 1) * 64, wn = (wave & 1) * 64;

  const int srow = t >> 3;
  const int swz = ((t & 7) ^ (srow & 7)) * 8;
  const u16* gA = A + (long)(m0 + srow) * 512 + swz;
  const u16* gB = B + (long)(n0 + srow) * 512 + swz;
  u16* dA = lA + wave * 512;
  u16* dB = lB + wave * 512;

  floatx4 acc[4][4];
#pragma unroll
  for (int x = 0; x < 4; ++x)
#pragma unroll
    for (int y = 0; y < 4; ++y) { floatx4 z = {0.f, 0.f, 0.f, 0.f}; acc[x][y] = z; }

#pragma unroll 1
  for (int kt = 0; kt < 8; ++kt) {
    gload16(gA, dA);
    gload16(gA + 32L * 512, dA + 2048);
    gload16(gA + 64L * 512, dA + 4096);
    gload16(gA + 96L * 512, dA + 6144);
    gload16(gB, dB);
    gload16(gB + 32L * 512, dB + 2048);
    gload16(gB + 64L * 512, dB + 4096);
    gload16(gB + 96L * 512, dB + 6144);
    gA += 64; gB += 64;
    __syncthreads();
#pragma unroll
    for (int ks = 0; ks < 2; ++ks) {
      short8 af[4], bfr[4];
      const int csl = ((ks * 4 + fq) ^ (fm & 7)) * 8;
#pragma unroll
      for (int x = 0; x < 4; ++x)
        af[x] = *(const short8*)&lA[(wm + x * 16 + fm) * 64 + csl];
#pragma unroll
      for (int y = 0; y < 4; ++y)
        bfr[y] = *(const short8*)&lB[(wn + y * 16 + fm) * 64 + csl];
#pragma unroll
      for (int x = 0; x < 4; ++x)
#pragma unroll
        for (int y = 0; y < 4; ++y)
          acc[x][y] = __builtin_amdgcn_mfma_f32_16x16x32_bf16(af[x], bfr[y], acc[x][y], 0, 0, 0);
    }
    __syncthreads();
  }

  int cs[4];
#pragma unroll
  for (int y = 0; y < 4; ++y) cs[y] = ((((wn >> 4) + y) ^ fq) * 16) + fm;

  float s4[4] = {0.f, 0.f, 0.f, 0.f};
#pragma unroll
  for (int x = 0; x < 4; ++x)
#pragma unroll
    for (int r = 0; r < 4; ++r) {
      int rowl = wm + x * 16 + fq * 4 + r;
      float e0 = __builtin_amdgcn_exp2f(acc[x][0][r]);
      float e1 = __builtin_amdgcn_exp2f(acc[x][1][r]);
      float e2 = __builtin_amdgcn_exp2f(acc[x][2][r]);
      float e3 = __builtin_amdgcn_exp2f(acc[x][3][r]);
      s4[0] += e0; s4[1] += e1; s4[2] += e2; s4[3] += e3;
      unsigned p01 = cvt_pk_bf16(e0, e1);
      unsigned p23 = cvt_pk_bf16(e2, e3);
      smem[rowl * 128 + cs[0]] = (u16)p01;
      smem[rowl * 128 + cs[1]] = (u16)(p01 >> 16);
      smem[rowl * 128 + cs[2]] = (u16)p23;
      smem[rowl * 128 + cs[3]] = (u16)(p23 >> 16);
    }
#pragma unroll
  for (int y = 0; y < 4; ++y) {
    s4[y] += __shfl_xor(s4[y], 16, 64);
    s4[y] += __shfl_xor(s4[y], 32, 64);
  }
  __syncthreads();
  u16* Eg = E + (long)b * (1024L * 2048);
#pragma unroll
  for (int p = 0; p < 8; ++p) {
    int rowl = p * 16 + (t >> 4);
    int c = t & 15;
    int q = (rowl >> 2) & 3;
    short8 v = *(const short8*)&smem[rowl * 128 + (((c >> 1) ^ q) * 16) + (c & 1) * 8];
    *(short8*)(Eg + (long)(m0 + rowl) * 2048 + n0 + c * 8) = v;
  }
  if (fq == 0) {
#pragma unroll
    for (int y = 0; y < 4; ++y)
      atomicAdd(&Z[b * 2048 + n0 + wn + y * 16 + fm], s4[y]);
  }
}

// ------- PV: out[b][i][d] = (sum_j E[i,j]*vT[d,j]/Z[j] + eps*colV[d])*invR --
// 64x64 tile, BK=64, two-barrier schedule, T14 issue-early V prefetch.
__global__ __launch_bounds__(256) void gemm_pv(const u16* __restrict__ E,
    const u16* __restrict__ V, const float* __restrict__ colV,
    const float* __restrict__ Z, float* __restrict__ out) {
  __shared__ u16 smem[8192];     // lA | lB in K-loop; 64x64 fp32 tile after
  __shared__ u16 sZb[2048];
  u16* lA = smem;
  u16* lB = smem + 4096;
  const int id = blockIdx.x;
  const int b = id & 7;
  const int m0 = ((id >> 3) & 15) * 64, n0 = (id >> 7) * 64;
  const int t = threadIdx.x, wave = t >> 6, lane = t & 63;
  const int fm = lane & 15, fq = lane >> 4;
  const int wm = (wave >> 1) * 32, wn = (wave & 1) * 32;

  {
    int i = t * 8;
    float4 z0 = *(const float4*)(Z + b * 2048 + i);
    float4 z1 = *(const float4*)(Z + b * 2048 + i + 4);
    union { unsigned u[4]; short8 s8; } o;
    o.u[0] = cvt_pk_bf16(__builtin_amdgcn_rcpf(z0.x), __builtin_amdgcn_rcpf(z0.y));
    o.u[1] = cvt_pk_bf16(__builtin_amdgcn_rcpf(z0.z), __builtin_amdgcn_rcpf(z0.w));
    o.u[2] = cvt_pk_bf16(__builtin_amdgcn_rcpf(z1.x), __builtin_amdgcn_rcpf(z1.y));
    o.u[3] = cvt_pk_bf16(__builtin_amdgcn_rcpf(z1.z), __builtin_amdgcn_rcpf(z1.w));
    *(short8*)&sZb[i] = o.s8;
  }
  __syncthreads();   // loop scale reads sZb

  const int srow = t >> 3;
  const int swz = ((t & 7) ^ (srow & 7)) * 8;
  const u16* gA = E + (long)b * (1024L * 2048) + (long)(m0 + srow) * 2048 + swz;
  const u16* gB = V + (long)b * (512L * 2048) + (long)(n0 + srow) * 2048 + swz;
  u16* dA = lA + wave * 512;
  u16* dB = lB + wave * 512;

  floatx4 acc[2][2];
  floatx4 accR[2];
#pragma unroll
  for (int x = 0; x < 2; ++x) {
    floatx4 z = {0.f, 0.f, 0.f, 0.f};
    accR[x] = z;
#pragma unroll
    for (int y = 0; y < 2; ++y) acc[x][y] = z;
  }

  // V tile 0 -> registers
  short8 rv0 = *(const short8*)gB;
  short8 rv1 = *(const short8*)(gB + 32L * 2048);
  gB += 64;

#pragma unroll 1
  for (int kt = 0; kt < 32; ++kt) {
    gload16(gA, dA);
    gload16(gA + 32L * 2048, dA + 2048);
    gA += 64;
    short8 zr = *(const short8*)&sZb[kt * 64 + swz];
    union { unsigned u[4]; short8 s8; } o0, o1;
#pragma unroll
    for (int e = 0; e < 4; ++e) {
      float zlo = bf2f((u16)zr[2 * e]), zhi = bf2f((u16)zr[2 * e + 1]);
      o0.u[e] = cvt_pk_bf16(bf2f((u16)rv0[2 * e]) * zlo,
                            bf2f((u16)rv0[2 * e + 1]) * zhi);
      o1.u[e] = cvt_pk_bf16(bf2f((u16)rv1[2 * e]) * zlo,
                            bf2f((u16)rv1[2 * e + 1]) * zhi);
    }
    u16* db = dB + (lane << 3);
    *(short8*)db = o0.s8;
    *(short8*)(db + 2048) = o1.s8;
    if (kt < 31) {
      rv0 = *(const short8*)gB;
      rv1 = *(const short8*)(gB + 32L * 2048);
      gB += 64;
    }
    __syncthreads();
#pragma unroll
    for (int ks = 0; ks < 2; ++ks) {
      short8 af[2], bfr[2];
      const int chunk = ks * 4 + fq;
      const int csl = (chunk ^ (fm & 7)) * 8;
#pragma unroll
      for (int x = 0; x < 2; ++x)
        af[x] = *(const short8*)&lA[(wm + x * 16 + fm) * 64 + csl];
#pragma unroll
      for (int y = 0; y < 2; ++y)
        bfr[y] = *(const short8*)&lB[(wn + y * 16 + fm) * 64 + csl];
      short8 zf = *(const short8*)&sZb[kt * 64 + chunk * 8];
#pragma unroll
      for (int x = 0; x < 2; ++x) {
#pragma unroll
        for (int y = 0; y < 2; ++y)
          acc[x][y] = __builtin_amdgcn_mfma_f32_16x16x32_bf16(af[x], bfr[y], acc[x][y], 0, 0, 0);
        accR[x] = __builtin_amdgcn_mfma_f32_16x16x32_bf16(af[x], zf, accR[x], 0, 0, 0);
      }
    }
    __syncthreads();
  }

  float cv[2];
#pragma unroll
  for (int y = 0; y < 2; ++y) cv[y] = colV[b * 512 + n0 + wn + y * 16 + fm];
  float* sO = (float*)smem;
#pragma unroll
  for (int x = 0; x < 2; ++x)
#pragma unroll
    for (int r = 0; r < 4; ++r) {
      float invR = __builtin_amdgcn_rcpf(accR[x][r] + 2048.f * 1e-8f);
      int rowl = wm + x * 16 + fq * 4 + r;
#pragma unroll
      for (int y = 0; y < 2; ++y) {
        const int cblk = (wn >> 4) + y;
        sO[rowl * 64 + ((cblk ^ fq) * 16) + fm] =
            (acc[x][y][r] + 1e-8f * cv[y]) * invR;
      }
    }
  __syncthreads();
  float* og = out + (long)b * (1024L * 512);
#pragma unroll
  for (int p = 0; p < 4; ++p) {
    int rowl = p * 16 + (t >> 4);
    int c = t & 15;
    int q = (rowl >> 2) & 3;
    float4 v = *(const float4*)&sO[rowl * 64 + (((c >> 2) ^ q) * 16) + (c & 3) * 4];
    *(float4*)(og + (long)(m0 + rowl) * 512 + n0 + c * 4) = v;
  }
}

extern "C" void kernel_launch(void* const* d_in, const int* in_sizes, int n_in,
                              void* d_out, int out_size, void* d_ws, size_t ws_size,
                              hipStream_t stream) {
  const float* inputs  = (const float*)d_in[0];
  const float* context = (const float*)d_in[1];
  const float* ln_in_g = (const float*)d_in[2];
  const float* ln_in_b = (const float*)d_in[3];
  const float* ln_ctx_g = (const float*)d_in[4];
  const float* ln_ctx_b = (const float*)d_in[5];
  const float* Wq = (const float*)d_in[6];
  const float* bq = (const float*)d_in[7];
  const float* Wk = (const float*)d_in[8];
  const float* bk = (const float*)d_in[9];
  const float* Wv = (const float*)d_in[10];
  const float* bv = (const float*)d_in[11];
  float* out = (float*)d_out;

  u16* ws = (u16*)d_ws;
  u16* xb  = ws;                        // [8192][512]
  u16* qb  = xb + 8192L * 512;          // [8192][512]
  u16* cb  = qb + 8192L * 512;          // [16384][512]
  u16* wqb = cb + 16384L * 512;         // [512][512]
  u16* wkb = wqb + 512L * 512;
  u16* wvb = wkb + 512L * 512;
  u16* kb  = wvb + 512L * 512;          // [16384][512]
  u16* vTs = kb + 16384L * 512;         // [8][512][2048] raw (unscaled)
  u16* E   = vTs + 8L * 512 * 2048;     // [8][1024][2048]
  float* Z    = (float*)(E + 8L * 1024 * 2048);   // [8][2048] raw col sums
  float* colV = Z + 8L * 2048;                    // [8][512]

  // 512^-0.5 * log2(e): fold scale AND exp->exp2 factor into Wq/bq
  const float qsc = (float)(0.04419417382415922 * 1.4426950408889634);

  // 1: LN(inputs)+LN(context) wave-per-row + weight cvt + zero Z/colV
  ln_prep<<<6932, 256, 0, stream>>>(inputs, ln_in_g, ln_in_b, xb,
                                    context, ln_ctx_g, ln_ctx_b, cb,
                                    Wq, Wk, Wv, wqb, wkb, wvb, Z, qsc);
  // 2: q-proj + merged k/v-proj (cb staged once for both) -> qb, kb, vT, colV
  proj_all<<<1280, 256, 0, stream>>>(xb, wqb, bq, qb,
                                     cb, wkb, bk, kb,
                                     wvb, bv, vTs, colV, qsc);
  // 3: pure QK -> E, Z (1024 blocks = exactly 4/CU)
  gemm_qk<<<1024, 256, 0, stream>>>(qb, kb, E, Z);
  // 4: PV, 2-barrier schedule, inline R, inline 1/Z V-scaling, T14 issue-early
  gemm_pv<<<1024, 256, 0, stream>>>(E, vTs, colV, Z, out);
}

// Round 13
// 207.131 us; speedup vs baseline: 1.0272x; 1.0272x over previous
//
#include <hip/hip_runtime.h>

using u16 = unsigned short;
typedef __attribute__((ext_vector_type(8))) short short8;
typedef __attribute__((ext_vector_type(4))) float floatx4;

#define NQ 1024
#define NK 2048
#define DD 512

__device__ __forceinline__ float bf2f(u16 u) {
  union { unsigned u; float f; } x; x.u = ((unsigned)u) << 16; return x.f;
}
// packed RTNE f32x2 -> bf16x2 (bits[15:0]=lo, [31:16]=hi)
__device__ __forceinline__ unsigned cvt_pk_bf16(float lo, float hi) {
  unsigned r;
  asm("v_cvt_pk_bf16_f32 %0, %1, %2" : "=v"(r) : "v"(lo), "v"(hi));
  return r;
}
__device__ __forceinline__ float wave_sum(float v) {
#pragma unroll
  for (int off = 32; off > 0; off >>= 1) v += __shfl_down(v, off, 64);
  return v;
}
__device__ __forceinline__ void gload16(const u16* g, const u16* l) {
  __builtin_amdgcn_global_load_lds(
      (const __attribute__((address_space(1))) void*)g,
      (__attribute__((address_space(3))) void*)l, 16, 0, 0);
}

// ---- fused: wave-per-row LN (inputs+context) + weight cvt + zero Z/colV ----
__global__ __launch_bounds__(256) void ln_prep(
    const float* __restrict__ X1, const float* __restrict__ G1,
    const float* __restrict__ B1, u16* __restrict__ Y1,
    const float* __restrict__ X2, const float* __restrict__ G2,
    const float* __restrict__ B2, u16* __restrict__ Y2,
    const float* __restrict__ Wq, const float* __restrict__ Wk,
    const float* __restrict__ Wv, u16* __restrict__ wqb,
    u16* __restrict__ wkb, u16* __restrict__ wvb, float* __restrict__ Zero,
    float qsc) {
  const int bx = blockIdx.x;
  const int t = threadIdx.x;
  if (bx >= 6144) {
    int e = bx - 6144;
    if (e < 768) {
      const float* src = e < 256 ? Wq : (e < 512 ? Wk : Wv);
      u16* dst = e < 256 ? wqb : (e < 512 ? wkb : wvb);
      const float ws = e < 256 ? qsc : 1.f;
      int i = ((e & 255) * 256 + t) * 4;
      float4 v = *(const float4*)(src + i);
      union { unsigned u[2]; ushort4 s; } ou;
      ou.u[0] = cvt_pk_bf16(v.x * ws, v.y * ws);
      ou.u[1] = cvt_pk_bf16(v.z * ws, v.w * ws);
      *(ushort4*)(dst + i) = ou.s;
    } else {
      int i = ((e - 768) * 256 + t) * 4;
      float4 z = {0.f, 0.f, 0.f, 0.f};
      *(float4*)(Zero + i) = z;
    }
    return;
  }
  const int wave = t >> 6, lane = t & 63;
  int row = bx * 4 + wave;
  const float *X, *G, *Bv; u16* Y;
  if (row < 8192) { X = X1; G = G1; Bv = B1; Y = Y1; }
  else { row -= 8192; X = X2; G = G2; Bv = B2; Y = Y2; }
  const float4* Xp = (const float4*)(X + (long)row * DD);
  float4 v0 = Xp[lane * 2], v1 = Xp[lane * 2 + 1];
  float s = v0.x + v0.y + v0.z + v0.w + v1.x + v1.y + v1.z + v1.w;
  float ss = v0.x * v0.x + v0.y * v0.y + v0.z * v0.z + v0.w * v0.w +
             v1.x * v1.x + v1.y * v1.y + v1.z * v1.z + v1.w * v1.w;
  s = wave_sum(s);  s = __shfl(s, 0, 64);
  ss = wave_sum(ss); ss = __shfl(ss, 0, 64);
  float mu = s * (1.f / DD);
  float var = ss * (1.f / DD) - mu * mu;
  float rs = rsqrtf(var + 1e-5f);
  const float4* Gp = (const float4*)G;
  const float4* Bp = (const float4*)Bv;
  float4 g0 = Gp[lane * 2], g1 = Gp[lane * 2 + 1];
  float4 b0 = Bp[lane * 2], b1 = Bp[lane * 2 + 1];
  union { unsigned u[4]; short8 s8; } ou;
  ou.u[0] = cvt_pk_bf16((v0.x - mu) * rs * g0.x + b0.x,
                        (v0.y - mu) * rs * g0.y + b0.y);
  ou.u[1] = cvt_pk_bf16((v0.z - mu) * rs * g0.z + b0.z,
                        (v0.w - mu) * rs * g0.w + b0.w);
  ou.u[2] = cvt_pk_bf16((v1.x - mu) * rs * g1.x + b1.x,
                        (v1.y - mu) * rs * g1.y + b1.y);
  ou.u[3] = cvt_pk_bf16((v1.z - mu) * rs * g1.z + b1.z,
                        (v1.w - mu) * rs * g1.w + b1.w);
  *(short8*)(Y + (long)row * DD + lane * 8) = ou.s8;
}

// ---- proj_all: q-proj (blocks 0..255, 128x128) + merged k&v proj
// (256..1279, 128 ctx-rows x 64 d-cols, cb staged ONCE for both Wk and Wv).
// XCD-affinity mappings: blocks sharing an A-panel share blockIdx&7 (same XCD
// L2). sV transposed stage uses stride 136 (bank-decorrelated, 16B-aligned).
__global__ __launch_bounds__(256) void proj_all(
    const u16* __restrict__ xb, const u16* __restrict__ wqb,
    const float* __restrict__ bq, u16* __restrict__ qb,
    const u16* __restrict__ cb, const u16* __restrict__ wkb,
    const float* __restrict__ bk, u16* __restrict__ kb,
    const u16* __restrict__ wvb, const float* __restrict__ bv,
    u16* __restrict__ vT, float* __restrict__ colV, float qsc) {
  __shared__ u16 smem[16896];
  const int bx = blockIdx.x;
  const int t = threadIdx.x, wave = t >> 6, lane = t & 63;
  const int fm = lane & 15, fq = lane >> 4;
  const int srow = t >> 3;
  const int swz = ((t & 7) ^ (srow & 7)) * 8;

  if (bx < 256) {
    // ---------------- q path: 128x128; m-panel sharers on same XCD ---------
    u16* lA = smem;
    u16* lB = smem + 8192;
    const int m0 = (bx & 63) * 128, n0 = (bx >> 6) * 128;
    const int wm = (wave >> 1) * 64, wn = (wave & 1) * 64;
    const u16* gA = xb + (long)(m0 + srow) * 512 + swz;
    const u16* gB = wqb + (long)(n0 + srow) * 512 + swz;
    u16* dA = lA + wave * 512;
    u16* dB = lB + wave * 512;

    floatx4 acc[4][4];
#pragma unroll
    for (int x = 0; x < 4; ++x)
#pragma unroll
      for (int y = 0; y < 4; ++y) { floatx4 z = {0.f,0.f,0.f,0.f}; acc[x][y] = z; }

#pragma unroll 1
    for (int kt = 0; kt < 8; ++kt) {
      gload16(gA, dA);
      gload16(gA + 32L * 512, dA + 2048);
      gload16(gA + 64L * 512, dA + 4096);
      gload16(gA + 96L * 512, dA + 6144);
      gload16(gB, dB);
      gload16(gB + 32L * 512, dB + 2048);
      gload16(gB + 64L * 512, dB + 4096);
      gload16(gB + 96L * 512, dB + 6144);
      gA += 64; gB += 64;
      __syncthreads();
#pragma unroll
      for (int ks = 0; ks < 2; ++ks) {
        short8 af[4], bfr[4];
        const int csl = ((ks * 4 + fq) ^ (fm & 7)) * 8;
#pragma unroll
        for (int x = 0; x < 4; ++x)
          af[x] = *(const short8*)&lA[(wm + x * 16 + fm) * 64 + csl];
#pragma unroll
        for (int y = 0; y < 4; ++y)
          bfr[y] = *(const short8*)&lB[(wn + y * 16 + fm) * 64 + csl];
#pragma unroll
        for (int x = 0; x < 4; ++x)
#pragma unroll
          for (int y = 0; y < 4; ++y)
            acc[x][y] = __builtin_amdgcn_mfma_f32_16x16x32_bf16(af[x], bfr[y], acc[x][y], 0, 0, 0);
      }
      __syncthreads();
    }

    float bs[4];
    int cs[4];
#pragma unroll
    for (int y = 0; y < 4; ++y) {
      bs[y] = bq[n0 + wn + y * 16 + fm] * qsc;
      cs[y] = ((((wn >> 4) + y) ^ fq) * 16) + fm;
    }
#pragma unroll
    for (int x = 0; x < 4; ++x)
#pragma unroll
      for (int r = 0; r < 4; ++r) {
        int rowl = wm + x * 16 + fq * 4 + r;
        unsigned p01 = cvt_pk_bf16(acc[x][0][r] + bs[0], acc[x][1][r] + bs[1]);
        unsigned p23 = cvt_pk_bf16(acc[x][2][r] + bs[2], acc[x][3][r] + bs[3]);
        smem[rowl * 128 + cs[0]] = (u16)p01;
        smem[rowl * 128 + cs[1]] = (u16)(p01 >> 16);
        smem[rowl * 128 + cs[2]] = (u16)p23;
        smem[rowl * 128 + cs[3]] = (u16)(p23 >> 16);
      }
    __syncthreads();
#pragma unroll
    for (int p = 0; p < 8; ++p) {
      int rowl = p * 16 + (t >> 4);
      int c = t & 15;
      int q = (rowl >> 2) & 3;
      short8 v = *(const short8*)&smem[rowl * 128 + (((c >> 1) ^ q) * 16) + (c & 1) * 8];
      *(short8*)(qb + (long)(m0 + rowl) * 512 + n0 + c * 8) = v;
    }
  } else {
    // -------- merged kv path: A=cb (128 rows), B=wkb & wvb (64 cols) -------
    // j0 = (e&127): cb-panel sharers (d0 = e>>7) share e&7 -> same XCD.
    const int e = bx - 256;
    const int j0 = (e & 127) * 128, d0 = (e >> 7) * 64;
    const int bb = j0 >> 11, j0c = j0 & 2047;
    u16* lA = smem;             // 128x64 u16 (16 KB)
    u16* lK = smem + 8192;      // 64x64  (8 KB)
    u16* lV = smem + 12288;     // 64x64  (8 KB)
    const int wm = (wave >> 1) * 64, wn = (wave & 1) * 32;
    const u16* gA = cb + (long)(j0 + srow) * 512 + swz;
    const u16* gK = wkb + (long)(d0 + srow) * 512 + swz;
    const u16* gV = wvb + (long)(d0 + srow) * 512 + swz;
    u16* dA = lA + wave * 512;
    u16* dK = lK + wave * 512;
    u16* dV = lV + wave * 512;

    floatx4 aK[4][2], aV[4][2];
#pragma unroll
    for (int x = 0; x < 4; ++x)
#pragma unroll
      for (int y = 0; y < 2; ++y) {
        floatx4 z = {0.f, 0.f, 0.f, 0.f};
        aK[x][y] = z; aV[x][y] = z;
      }

#pragma unroll 1
    for (int kt = 0; kt < 8; ++kt) {
      gload16(gA, dA);
      gload16(gA + 32L * 512, dA + 2048);
      gload16(gA + 64L * 512, dA + 4096);
      gload16(gA + 96L * 512, dA + 6144);
      gload16(gK, dK);
      gload16(gK + 32L * 512, dK + 2048);
      gload16(gV, dV);
      gload16(gV + 32L * 512, dV + 2048);
      gA += 64; gK += 64; gV += 64;
      __syncthreads();
#pragma unroll
      for (int ks = 0; ks < 2; ++ks) {
        short8 af[4], bk8[2], bv8[2];
        const int csl = ((ks * 4 + fq) ^ (fm & 7)) * 8;
#pragma unroll
        for (int x = 0; x < 4; ++x)
          af[x] = *(const short8*)&lA[(wm + x * 16 + fm) * 64 + csl];
#pragma unroll
        for (int y = 0; y < 2; ++y) {
          bk8[y] = *(const short8*)&lK[(wn + y * 16 + fm) * 64 + csl];
          bv8[y] = *(const short8*)&lV[(wn + y * 16 + fm) * 64 + csl];
        }
#pragma unroll
        for (int x = 0; x < 4; ++x)
#pragma unroll
          for (int y = 0; y < 2; ++y) {
            aK[x][y] = __builtin_amdgcn_mfma_f32_16x16x32_bf16(af[x], bk8[y], aK[x][y], 0, 0, 0);
            aV[x][y] = __builtin_amdgcn_mfma_f32_16x16x32_bf16(af[x], bv8[y], aV[x][y], 0, 0, 0);
          }
      }
      __syncthreads();
    }

    // epilogue: sK [128 j][64 d] + sV [64 d][136-stride cols j]
    u16* sK = smem;            // 16 KB
    u16* sV = smem + 8192;     // 64*136 u16 = 17 KB
    float bks[2], bvs[2];
    int dloc[2];
#pragma unroll
    for (int y = 0; y < 2; ++y) {
      dloc[y] = wn + y * 16 + fm;
      bks[y] = bk[d0 + dloc[y]];
      bvs[y] = bv[d0 + dloc[y]];
    }
    float cva[2] = {0.f, 0.f};
#pragma unroll
    for (int x = 0; x < 4; ++x)
#pragma unroll
      for (int r = 0; r < 4; ++r) {
        int rowl = wm + x * 16 + fq * 4 + r;   // j local 0..127
        float vk0 = aK[x][0][r] + bks[0];
        float vk1 = aK[x][1][r] + bks[1];
        float vv0 = aV[x][0][r] + bvs[0];
        float vv1 = aV[x][1][r] + bvs[1];
        cva[0] += vv0; cva[1] += vv1;
        unsigned pk = cvt_pk_bf16(vk0, vk1);
        unsigned pv = cvt_pk_bf16(vv0, vv1);
        const int ck0 = ((((wn >> 4) + 0) ^ fq) * 16) + fm;
        const int ck1 = ((((wn >> 4) + 1) ^ fq) * 16) + fm;
        sK[rowl * 64 + ck0] = (u16)pk;
        sK[rowl * 64 + ck1] = (u16)(pk >> 16);
        const int jblk = rowl >> 4, jin = rowl & 15;
        sV[dloc[0] * 136 + ((jblk ^ (dloc[0] & 7)) * 16) + jin] = (u16)pv;
        sV[dloc[1] * 136 + ((jblk ^ (dloc[1] & 7)) * 16) + jin] = (u16)(pv >> 16);
      }
    __syncthreads();
    // store kb: 128 rows x 64 cols
#pragma unroll
    for (int p = 0; p < 4; ++p) {
      int rowl = p * 32 + (t >> 3);
      int c = t & 7;
      int q = (rowl >> 2) & 3;
      short8 v = *(const short8*)&sK[rowl * 64 + (((c >> 1) ^ q) * 16) + (c & 1) * 8];
      *(short8*)(kb + (long)(j0 + rowl) * 512 + d0 + c * 8) = v;
    }
    // store vT: 64 rows (d) x 128 cols (j)
    u16* Vg = vT + (long)bb * (512L * 2048) + j0c;
#pragma unroll
    for (int p = 0; p < 4; ++p) {
      int d = p * 16 + (t >> 4);
      int c = t & 15;
      short8 v = *(const short8*)&sV[d * 136 + (((c >> 1) ^ (d & 7)) * 16) + (c & 1) * 8];
      *(short8*)(Vg + (long)(d0 + d) * 2048 + c * 8) = v;
    }
    // colV: reduce over fq within wave, atomic per wave half
#pragma unroll
    for (int y = 0; y < 2; ++y) {
      float s = cva[y];
      s += __shfl_xor(s, 16, 64);
      s += __shfl_xor(s, 32, 64);
      if (fq == 0) atomicAdd(&colV[bb * 512 + d0 + dloc[y]], s);
    }
  }
}

// ---------------- QK: E = exp2(q.k^T), Z[j] col sums (atomics) --------------
__global__ __launch_bounds__(256) void gemm_qk(
    const u16* __restrict__ qb, const u16* __restrict__ kb,
    u16* __restrict__ E, float* __restrict__ Z) {
  __shared__ u16 smem[16384];
  u16* lA = smem;
  u16* lB = smem + 8192;

  const int bx = blockIdx.x;
  const int b = bx & 7;
  const int n0 = ((bx >> 3) & 15) * 128;
  const int m0 = (bx >> 7) * 128;
  const u16* A = qb + (long)b * (1024L * 512);
  const u16* B = kb + (long)b * (2048L * 512);

  const int t = threadIdx.x, wave = t >> 6, lane = t & 63;
  const int fm = lane & 15, fq = lane >> 4;
  const int wm = (wave >> 1) * 64, wn = (wave & 1) * 64;

  const int srow = t >> 3;
  const int swz = ((t & 7) ^ (srow & 7)) * 8;
  const u16* gA = A + (long)(m0 + srow) * 512 + swz;
  const u16* gB = B + (long)(n0 + srow) * 512 + swz;
  u16* dA = lA + wave * 512;
  u16* dB = lB + wave * 512;

  floatx4 acc[4][4];
#pragma unroll
  for (int x = 0; x < 4; ++x)
#pragma unroll
    for (int y = 0; y < 4; ++y) { floatx4 z = {0.f, 0.f, 0.f, 0.f}; acc[x][y] = z; }

#pragma unroll 1
  for (int kt = 0; kt < 8; ++kt) {
    gload16(gA, dA);
    gload16(gA + 32L * 512, dA + 2048);
    gload16(gA + 64L * 512, dA + 4096);
    gload16(gA + 96L * 512, dA + 6144);
    gload16(gB, dB);
    gload16(gB + 32L * 512, dB + 2048);
    gload16(gB + 64L * 512, dB + 4096);
    gload16(gB + 96L * 512, dB + 6144);
    gA += 64; gB += 64;
    __syncthreads();
#pragma unroll
    for (int ks = 0; ks < 2; ++ks) {
      short8 af[4], bfr[4];
      const int csl = ((ks * 4 + fq) ^ (fm & 7)) * 8;
#pragma unroll
      for (int x = 0; x < 4; ++x)
        af[x] = *(const short8*)&lA[(wm + x * 16 + fm) * 64 + csl];
#pragma unroll
      for (int y = 0; y < 4; ++y)
        bfr[y] = *(const short8*)&lB[(wn + y * 16 + fm) * 64 + csl];
#pragma unroll
      for (int x = 0; x < 4; ++x)
#pragma unroll
        for (int y = 0; y < 4; ++y)
          acc[x][y] = __builtin_amdgcn_mfma_f32_16x16x32_bf16(af[x], bfr[y], acc[x][y], 0, 0, 0);
    }
    __syncthreads();
  }

  int cs[4];
#pragma unroll
  for (int y = 0; y < 4; ++y) cs[y] = ((((wn >> 4) + y) ^ fq) * 16) + fm;

  float s4[4] = {0.f, 0.f, 0.f, 0.f};
#pragma unroll
  for (int x = 0; x < 4; ++x)
#pragma unroll
    for (int r = 0; r < 4; ++r) {
      int rowl = wm + x * 16 + fq * 4 + r;
      float e0 = __builtin_amdgcn_exp2f(acc[x][0][r]);
      float e1 = __builtin_amdgcn_exp2f(acc[x][1][r]);
      float e2 = __builtin_amdgcn_exp2f(acc[x][2][r]);
      float e3 = __builtin_amdgcn_exp2f(acc[x][3][r]);
      s4[0] += e0; s4[1] += e1; s4[2] += e2; s4[3] += e3;
      unsigned p01 = cvt_pk_bf16(e0, e1);
      unsigned p23 = cvt_pk_bf16(e2, e3);
      smem[rowl * 128 + cs[0]] = (u16)p01;
      smem[rowl * 128 + cs[1]] = (u16)(p01 >> 16);
      smem[rowl * 128 + cs[2]] = (u16)p23;
      smem[rowl * 128 + cs[3]] = (u16)(p23 >> 16);
    }
#pragma unroll
  for (int y = 0; y < 4; ++y) {
    s4[y] += __shfl_xor(s4[y], 16, 64);
    s4[y] += __shfl_xor(s4[y], 32, 64);
  }
  __syncthreads();
  u16* Eg = E + (long)b * (1024L * 2048);
#pragma unroll
  for (int p = 0; p < 8; ++p) {
    int rowl = p * 16 + (t >> 4);
    int c = t & 15;
    int q = (rowl >> 2) & 3;
    short8 v = *(const short8*)&smem[rowl * 128 + (((c >> 1) ^ q) * 16) + (c & 1) * 8];
    *(short8*)(Eg + (long)(m0 + rowl) * 2048 + n0 + c * 8) = v;
  }
  if (fq == 0) {
#pragma unroll
    for (int y = 0; y < 4; ++y)
      atomicAdd(&Z[b * 2048 + n0 + wn + y * 16 + fm], s4[y]);
  }
}

// ------- PV: out[b][i][d] = (sum_j E[i,j]*vT[d,j]/Z[j] + eps*colV[d])*invR --
// 64x64 tile, BK=64, two-barrier schedule, T14 issue-early V prefetch.
__global__ __launch_bounds__(256) void gemm_pv(const u16* __restrict__ E,
    const u16* __restrict__ V, const float* __restrict__ colV,
    const float* __restrict__ Z, float* __restrict__ out) {
  __shared__ u16 smem[8192];     // lA | lB in K-loop; 64x64 fp32 tile after
  __shared__ u16 sZb[2048];
  u16* lA = smem;
  u16* lB = smem + 4096;
  const int id = blockIdx.x;
  const int b = id & 7;
  const int m0 = ((id >> 3) & 15) * 64, n0 = (id >> 7) * 64;
  const int t = threadIdx.x, wave = t >> 6, lane = t & 63;
  const int fm = lane & 15, fq = lane >> 4;
  const int wm = (wave >> 1) * 32, wn = (wave & 1) * 32;

  {
    int i = t * 8;
    float4 z0 = *(const float4*)(Z + b * 2048 + i);
    float4 z1 = *(const float4*)(Z + b * 2048 + i + 4);
    union { unsigned u[4]; short8 s8; } o;
    o.u[0] = cvt_pk_bf16(__builtin_amdgcn_rcpf(z0.x), __builtin_amdgcn_rcpf(z0.y));
    o.u[1] = cvt_pk_bf16(__builtin_amdgcn_rcpf(z0.z), __builtin_amdgcn_rcpf(z0.w));
    o.u[2] = cvt_pk_bf16(__builtin_amdgcn_rcpf(z1.x), __builtin_amdgcn_rcpf(z1.y));
    o.u[3] = cvt_pk_bf16(__builtin_amdgcn_rcpf(z1.z), __builtin_amdgcn_rcpf(z1.w));
    *(short8*)&sZb[i] = o.s8;
  }
  __syncthreads();   // loop scale reads sZb

  const int srow = t >> 3;
  const int swz = ((t & 7) ^ (srow & 7)) * 8;
  const u16* gA = E + (long)b * (1024L * 2048) + (long)(m0 + srow) * 2048 + swz;
  const u16* gB = V + (long)b * (512L * 2048) + (long)(n0 + srow) * 2048 + swz;
  u16* dA = lA + wave * 512;
  u16* dB = lB + wave * 512;

  floatx4 acc[2][2];
  floatx4 accR[2];
#pragma unroll
  for (int x = 0; x < 2; ++x) {
    floatx4 z = {0.f, 0.f, 0.f, 0.f};
    accR[x] = z;
#pragma unroll
    for (int y = 0; y < 2; ++y) acc[x][y] = z;
  }

  // V tile 0 -> registers
  short8 rv0 = *(const short8*)gB;
  short8 rv1 = *(const short8*)(gB + 32L * 2048);
  gB += 64;

#pragma unroll 1
  for (int kt = 0; kt < 32; ++kt) {
    gload16(gA, dA);
    gload16(gA + 32L * 2048, dA + 2048);
    gA += 64;
    short8 zr = *(const short8*)&sZb[kt * 64 + swz];
    union { unsigned u[4]; short8 s8; } o0, o1;
#pragma unroll
    for (int e = 0; e < 4; ++e) {
      float zlo = bf2f((u16)zr[2 * e]), zhi = bf2f((u16)zr[2 * e + 1]);
      o0.u[e] = cvt_pk_bf16(bf2f((u16)rv0[2 * e]) * zlo,
                            bf2f((u16)rv0[2 * e + 1]) * zhi);
      o1.u[e] = cvt_pk_bf16(bf2f((u16)rv1[2 * e]) * zlo,
                            bf2f((u16)rv1[2 * e + 1]) * zhi);
    }
    u16* db = dB + (lane << 3);
    *(short8*)db = o0.s8;
    *(short8*)(db + 2048) = o1.s8;
    if (kt < 31) {
      rv0 = *(const short8*)gB;
      rv1 = *(const short8*)(gB + 32L * 2048);
      gB += 64;
    }
    __syncthreads();
#pragma unroll
    for (int ks = 0; ks < 2; ++ks) {
      short8 af[2], bfr[2];
      const int chunk = ks * 4 + fq;
      const int csl = (chunk ^ (fm & 7)) * 8;
#pragma unroll
      for (int x = 0; x < 2; ++x)
        af[x] = *(const short8*)&lA[(wm + x * 16 + fm) * 64 + csl];
#pragma unroll
      for (int y = 0; y < 2; ++y)
        bfr[y] = *(const short8*)&lB[(wn + y * 16 + fm) * 64 + csl];
      short8 zf = *(const short8*)&sZb[kt * 64 + chunk * 8];
#pragma unroll
      for (int x = 0; x < 2; ++x) {
#pragma unroll
        for (int y = 0; y < 2; ++y)
          acc[x][y] = __builtin_amdgcn_mfma_f32_16x16x32_bf16(af[x], bfr[y], acc[x][y], 0, 0, 0);
        accR[x] = __builtin_amdgcn_mfma_f32_16x16x32_bf16(af[x], zf, accR[x], 0, 0, 0);
      }
    }
    __syncthreads();
  }

  float cv[2];
#pragma unroll
  for (int y = 0; y < 2; ++y) cv[y] = colV[b * 512 + n0 + wn + y * 16 + fm];
  float* sO = (float*)smem;
#pragma unroll
  for (int x = 0; x < 2; ++x)
#pragma unroll
    for (int r = 0; r < 4; ++r) {
      float invR = __builtin_amdgcn_rcpf(accR[x][r] + 2048.f * 1e-8f);
      int rowl = wm + x * 16 + fq * 4 + r;
#pragma unroll
      for (int y = 0; y < 2; ++y) {
        const int cblk = (wn >> 4) + y;
        sO[rowl * 64 + ((cblk ^ fq) * 16) + fm] =
            (acc[x][y][r] + 1e-8f * cv[y]) * invR;
      }
    }
  __syncthreads();
  float* og = out + (long)b * (1024L * 512);
#pragma unroll
  for (int p = 0; p < 4; ++p) {
    int rowl = p * 16 + (t >> 4);
    int c = t & 15;
    int q = (rowl >> 2) & 3;
    float4 v = *(const float4*)&sO[rowl * 64 + (((c >> 2) ^ q) * 16) + (c & 3) * 4];
    *(float4*)(og + (long)(m0 + rowl) * 512 + n0 + c * 4) = v;
  }
}

extern "C" void kernel_launch(void* const* d_in, const int* in_sizes, int n_in,
                              void* d_out, int out_size, void* d_ws, size_t ws_size,
                              hipStream_t stream) {
  const float* inputs  = (const float*)d_in[0];
  const float* context = (const float*)d_in[1];
  const float* ln_in_g = (const float*)d_in[2];
  const float* ln_in_b = (const float*)d_in[3];
  const float* ln_ctx_g = (const float*)d_in[4];
  const float* ln_ctx_b = (const float*)d_in[5];
  const float* Wq = (const float*)d_in[6];
  const float* bq = (const float*)d_in[7];
  const float* Wk = (const float*)d_in[8];
  const float* bk = (const float*)d_in[9];
  const float* Wv = (const float*)d_in[10];
  const float* bv = (const float*)d_in[11];
  float* out = (float*)d_out;

  u16* ws = (u16*)d_ws;
  u16* xb  = ws;                        // [8192][512]
  u16* qb  = xb + 8192L * 512;          // [8192][512]
  u16* cb  = qb + 8192L * 512;          // [16384][512]
  u16* wqb = cb + 16384L * 512;         // [512][512]
  u16* wkb = wqb + 512L * 512;
  u16* wvb = wkb + 512L * 512;
  u16* kb  = wvb + 512L * 512;          // [16384][512]
  u16* vTs = kb + 16384L * 512;         // [8][512][2048] raw (unscaled)
  u16* E   = vTs + 8L * 512 * 2048;     // [8][1024][2048]
  float* Z    = (float*)(E + 8L * 1024 * 2048);   // [8][2048] raw col sums
  float* colV = Z + 8L * 2048;                    // [8][512]

  // 512^-0.5 * log2(e): fold scale AND exp->exp2 factor into Wq/bq
  const float qsc = (float)(0.04419417382415922 * 1.4426950408889634);

  // 1: LN(inputs)+LN(context) wave-per-row + weight cvt + zero Z/colV
  ln_prep<<<6932, 256, 0, stream>>>(inputs, ln_in_g, ln_in_b, xb,
                                    context, ln_ctx_g, ln_ctx_b, cb,
                                    Wq, Wk, Wv, wqb, wkb, wvb, Z, qsc);
  // 2: q-proj + merged k/v-proj (cb staged once; XCD-affine tile maps)
  proj_all<<<1280, 256, 0, stream>>>(xb, wqb, bq, qb,
                                     cb, wkb, bk, kb,
                                     wvb, bv, vTs, colV, qsc);
  // 3: pure QK -> E, Z (1024 blocks = exactly 4/CU)
  gemm_qk<<<1024, 256, 0, stream>>>(qb, kb, E, Z);
  // 4: PV, 2-barrier schedule, inline R, inline 1/Z V-scaling, T14 issue-early
  gemm_pv<<<1024, 256, 0, stream>>>(E, vTs, colV, Z, out);
}